// Round 1
// baseline (143.679 us; speedup 1.0000x reference)
//
#include <hip/hip_runtime.h>

#define NQ 10

// ---------- helpers ----------
__device__ __forceinline__ float2 shflx(float2 v, int m) {
    float2 r;
    r.x = __shfl_xor(v.x, m, 64);
    r.y = __shfl_xor(v.y, m, 64);
    return r;
}

// General complex 1q gate on a LANE bit (mask M = 1<<(p-4), p in 4..9).
template<int M>
__device__ __forceinline__ void gate_lane(float2 st[16], int lane,
                                          float2 g00, float2 g01,
                                          float2 g10, float2 g11) {
    const bool hi = (lane & M) != 0;
    // hi=0: new = g00*mine + g01*partner ; hi=1: new = g11*mine + g10*partner
    const float2 cA = hi ? g11 : g00;
    const float2 cB = hi ? g10 : g01;
#pragma unroll
    for (int r = 0; r < 16; ++r) {
        float2 part = shflx(st[r], M);
        float2 s0 = st[r];
        float2 nv;
        nv.x = cA.x * s0.x - cA.y * s0.y + cB.x * part.x - cB.y * part.y;
        nv.y = cA.x * s0.y + cA.y * s0.x + cB.x * part.y + cB.y * part.x;
        st[r] = nv;
    }
}

// General complex 1q gate on a REGISTER bit (RB = 1<<p, p in 0..3).
template<int RB>
__device__ __forceinline__ void gate_reg(float2 st[16],
                                         float2 g00, float2 g01,
                                         float2 g10, float2 g11) {
#pragma unroll
    for (int r = 0; r < 16; ++r) {
        if (r & RB) continue;
        float2 a0 = st[r], a1 = st[r | RB];
        float2 n0, n1;
        n0.x = g00.x * a0.x - g00.y * a0.y + g01.x * a1.x - g01.y * a1.y;
        n0.y = g00.x * a0.y + g00.y * a0.x + g01.x * a1.y + g01.y * a1.x;
        n1.x = g10.x * a0.x - g10.y * a0.y + g11.x * a1.x - g11.y * a1.y;
        n1.y = g10.x * a0.y + g10.y * a0.x + g11.x * a1.y + g11.y * a1.x;
        st[r] = n0;
        st[r | RB] = n1;
    }
}

// Real RY gate on a LANE bit. g = [[c,-s],[s,c]]
template<int M>
__device__ __forceinline__ void ry_lane(float2 st[16], int lane, float c, float s) {
    const bool hi = (lane & M) != 0;
    const float cB = hi ? s : -s;   // coefficient on partner amplitude
#pragma unroll
    for (int r = 0; r < 16; ++r) {
        float2 part = shflx(st[r], M);
        st[r].x = c * st[r].x + cB * part.x;
        st[r].y = c * st[r].y + cB * part.y;
    }
}

// Real RY gate on a REGISTER bit.
template<int RB>
__device__ __forceinline__ void ry_reg(float2 st[16], float c, float s) {
#pragma unroll
    for (int r = 0; r < 16; ++r) {
        if (r & RB) continue;
        float2 a0 = st[r], a1 = st[r | RB];
        st[r].x = c * a0.x - s * a1.x;
        st[r].y = c * a0.y - s * a1.y;
        st[r | RB].x = s * a0.x + c * a1.x;
        st[r | RB].y = s * a0.y + c * a1.y;
    }
}

// CNOT: control lane bit MC, target lane bit MT.
template<int MC, int MT>
__device__ __forceinline__ void cnot_lane_lane(float2 st[16], int lane) {
    const bool sel = (lane & MC) != 0;
#pragma unroll
    for (int r = 0; r < 16; ++r) {
        float2 t = shflx(st[r], MT);
        st[r] = sel ? t : st[r];
    }
}

// CNOT: control lane bit MC, target register bit RB.
template<int MC, int RB>
__device__ __forceinline__ void cnot_lane_reg(float2 st[16], int lane) {
    const bool sel = (lane & MC) != 0;
#pragma unroll
    for (int r = 0; r < 16; ++r) {
        if (r & RB) continue;
        float2 lo = st[r], hi = st[r | RB];
        st[r]      = sel ? hi : lo;
        st[r | RB] = sel ? lo : hi;
    }
}

// CNOT: control register bit RC, target register bit RT — free permutation.
template<int RC, int RT>
__device__ __forceinline__ void cnot_reg_reg(float2 st[16]) {
#pragma unroll
    for (int r = 0; r < 16; ++r) {
        if ((r & RC) && !(r & RT)) {
            float2 t = st[r];
            st[r] = st[r | RT];
            st[r | RT] = t;
        }
    }
}

// CNOT: control register bit RC, target lane bit MT.
template<int RC, int MT>
__device__ __forceinline__ void cnot_reg_lane(float2 st[16]) {
#pragma unroll
    for (int r = 0; r < 16; ++r) {
        if (r & RC) st[r] = shflx(st[r], MT);
    }
}

// ---------- main kernel: one wave per batch sample ----------
__global__ __launch_bounds__(256)
void pqc_kernel(const float* __restrict__ x,
                const float* __restrict__ params,
                float* __restrict__ out, int B) {
    const int lane = threadIdx.x & 63;
    const int wave = threadIdx.x >> 6;
    const int b = blockIdx.x * 4 + wave;
    if (b >= B) return;

    // state: s = lane*16 + r ; qubit q <-> state bit p = 9-q
    float2 st[16];
#pragma unroll
    for (int r = 0; r < 16; ++r) st[r] = make_float2(0.f, 0.f);
    if (lane == 0) st[0].x = 1.0f;

    // ---- data encoding: RY(x[b,q]) ----
    const float* xb = x + (long)b * NQ;
    float c, s;
    __sincosf(0.5f * xb[0], &s, &c); ry_lane<32>(st, lane, c, s);
    __sincosf(0.5f * xb[1], &s, &c); ry_lane<16>(st, lane, c, s);
    __sincosf(0.5f * xb[2], &s, &c); ry_lane<8>(st, lane, c, s);
    __sincosf(0.5f * xb[3], &s, &c); ry_lane<4>(st, lane, c, s);
    __sincosf(0.5f * xb[4], &s, &c); ry_lane<2>(st, lane, c, s);
    __sincosf(0.5f * xb[5], &s, &c); ry_lane<1>(st, lane, c, s);
    __sincosf(0.5f * xb[6], &s, &c); ry_reg<8>(st, c, s);
    __sincosf(0.5f * xb[7], &s, &c); ry_reg<4>(st, c, s);
    __sincosf(0.5f * xb[8], &s, &c); ry_reg<2>(st, c, s);
    __sincosf(0.5f * xb[9], &s, &c); ry_reg<1>(st, c, s);

    // ---- variational layers ----
    for (int l = 0; l < 4; ++l) {
        const float* pl = params + l * 2 * NQ;
        float2 g00, g01, g10, g11;
#define MKGATE(q) { \
        float cy, sy, cz, sz; \
        __sincosf(0.5f * pl[(q)], &sy, &cy); \
        __sincosf(0.5f * pl[NQ + (q)], &sz, &cz); \
        g00 = make_float2( cy * cz, -cy * sz); \
        g01 = make_float2(-sy * cz,  sy * sz); \
        g10 = make_float2( sy * cz,  sy * sz); \
        g11 = make_float2( cy * cz,  cy * sz); }

        MKGATE(0); gate_lane<32>(st, lane, g00, g01, g10, g11);
        MKGATE(1); gate_lane<16>(st, lane, g00, g01, g10, g11);
        MKGATE(2); gate_lane<8>(st, lane, g00, g01, g10, g11);
        MKGATE(3); gate_lane<4>(st, lane, g00, g01, g10, g11);
        MKGATE(4); gate_lane<2>(st, lane, g00, g01, g10, g11);
        MKGATE(5); gate_lane<1>(st, lane, g00, g01, g10, g11);
        MKGATE(6); gate_reg<8>(st, g00, g01, g10, g11);
        MKGATE(7); gate_reg<4>(st, g00, g01, g10, g11);
        MKGATE(8); gate_reg<2>(st, g00, g01, g10, g11);
        MKGATE(9); gate_reg<1>(st, g00, g01, g10, g11);
#undef MKGATE

        // CNOT ring: (0,1)(1,2)...(8,9)(9,0); qubit q -> bit 9-q
        cnot_lane_lane<32, 16>(st, lane);
        cnot_lane_lane<16, 8>(st, lane);
        cnot_lane_lane<8, 4>(st, lane);
        cnot_lane_lane<4, 2>(st, lane);
        cnot_lane_lane<2, 1>(st, lane);
        cnot_lane_reg<1, 8>(st, lane);
        cnot_reg_reg<8, 4>(st);
        cnot_reg_reg<4, 2>(st);
        cnot_reg_reg<2, 1>(st);
        cnot_reg_lane<1, 32>(st);
    }

    // ---- expectation values <Z_q> ----
    float lane_sum = 0.f;
    float rs8 = 0.f, rs4 = 0.f, rs2 = 0.f, rs1 = 0.f;
#pragma unroll
    for (int r = 0; r < 16; ++r) {
        float p = st[r].x * st[r].x + st[r].y * st[r].y;
        lane_sum += p;
        rs8 += (r & 8) ? -p : p;
        rs4 += (r & 4) ? -p : p;
        rs2 += (r & 2) ? -p : p;
        rs1 += (r & 1) ? -p : p;
    }
    float outv[10];
    outv[0] = (lane & 32) ? -lane_sum : lane_sum;
    outv[1] = (lane & 16) ? -lane_sum : lane_sum;
    outv[2] = (lane & 8)  ? -lane_sum : lane_sum;
    outv[3] = (lane & 4)  ? -lane_sum : lane_sum;
    outv[4] = (lane & 2)  ? -lane_sum : lane_sum;
    outv[5] = (lane & 1)  ? -lane_sum : lane_sum;
    outv[6] = rs8;
    outv[7] = rs4;
    outv[8] = rs2;
    outv[9] = rs1;

#pragma unroll
    for (int k = 1; k < 64; k <<= 1) {
#pragma unroll
        for (int q = 0; q < 10; ++q) outv[q] += __shfl_xor(outv[q], k, 64);
    }

    if (lane == 0) {
#pragma unroll
        for (int q = 0; q < 10; ++q) out[(long)b * NQ + q] = outv[q];
    }
}

extern "C" void kernel_launch(void* const* d_in, const int* in_sizes, int n_in,
                              void* d_out, int out_size, void* d_ws, size_t ws_size,
                              hipStream_t stream) {
    const float* x = (const float*)d_in[0];       // [B, 10]
    const float* params = (const float*)d_in[1];  // [4, 20]
    float* out = (float*)d_out;                   // [B, 10]
    const int B = in_sizes[0] / NQ;               // 4096
    const int waves_per_block = 4;                // 256 threads
    const int grid = (B + waves_per_block - 1) / waves_per_block;
    pqc_kernel<<<grid, 256, 0, stream>>>(x, params, out, B);
}

// Round 2
// 105.136 us; speedup vs baseline: 1.3666x; 1.3666x over previous
//
#include <hip/hip_runtime.h>

#define NQ 10

// ---------- helpers ----------
__device__ __forceinline__ float2 cmul(float2 a, float2 b) {
    return make_float2(a.x * b.x - a.y * b.y, a.x * b.y + a.y * b.x);
}

__device__ __forceinline__ float2 shflx(float2 v, int m) {
    float2 r;
    r.x = __shfl_xor(v.x, m, 64);
    r.y = __shfl_xor(v.y, m, 64);
    return r;
}

__device__ __forceinline__ float2 bperm2(int addr, float2 v) {
    float2 r;
    r.x = __int_as_float(__builtin_amdgcn_ds_bpermute(addr, __float_as_int(v.x)));
    r.y = __int_as_float(__builtin_amdgcn_ds_bpermute(addr, __float_as_int(v.y)));
    return r;
}

// Real RY gate on a LANE bit. g = [[c,-s],[s,c]]
template<int M>
__device__ __forceinline__ void ry_lane(float2 st[16], int lane, float c, float s) {
    const bool hi = (lane & M) != 0;
    const float cB = hi ? s : -s;   // coefficient on partner amplitude
#pragma unroll
    for (int r = 0; r < 16; ++r) {
        float2 part = shflx(st[r], M);
        st[r].x = c * st[r].x + cB * part.x;
        st[r].y = c * st[r].y + cB * part.y;
    }
}

// Real RY gate on a REGISTER bit.
template<int RB>
__device__ __forceinline__ void ry_reg(float2 st[16], float c, float s) {
#pragma unroll
    for (int r = 0; r < 16; ++r) {
        if (r & RB) continue;
        float2 a0 = st[r], a1 = st[r | RB];
        st[r].x = c * a0.x - s * a1.x;
        st[r].y = c * a0.y - s * a1.y;
        st[r | RB].x = s * a0.x + c * a1.x;
        st[r | RB].y = s * a0.y + c * a1.y;
    }
}

// CNOT: control lane bit MC, target register bit RB.
template<int MC, int RB>
__device__ __forceinline__ void cnot_lane_reg(float2 st[16], int lane) {
    const bool sel = (lane & MC) != 0;
#pragma unroll
    for (int r = 0; r < 16; ++r) {
        if (r & RB) continue;
        float2 lo = st[r], hi = st[r | RB];
        st[r]      = sel ? hi : lo;
        st[r | RB] = sel ? lo : hi;
    }
}

// CNOT: control register bit RC, target register bit RT — free permutation.
template<int RC, int RT>
__device__ __forceinline__ void cnot_reg_reg(float2 st[16]) {
#pragma unroll
    for (int r = 0; r < 16; ++r) {
        if ((r & RC) && !(r & RT)) {
            float2 t = st[r];
            st[r] = st[r | RT];
            st[r | RT] = t;
        }
    }
}

// CNOT: control register bit RC, target lane bit MT.
template<int RC, int MT>
__device__ __forceinline__ void cnot_reg_lane(float2 st[16]) {
#pragma unroll
    for (int r = 0; r < 16; ++r) {
        if (r & RC) st[r] = shflx(st[r], MT);
    }
}

// 64-point Walsh-Hadamard transform across lanes: afterwards, the value in
// lane m equals sum_l (-1)^popc(m&l) v_l.
__device__ __forceinline__ float wht64(float v, int lane) {
#pragma unroll
    for (int k = 1; k < 64; k <<= 1) {
        float t = __shfl_xor(v, k, 64);
        v = (lane & k) ? (t - v) : (v + t);
    }
    return v;
}

// ---------- main kernel: one wave per batch sample ----------
// State layout: s = lane*16 + r ; qubit q <-> state bit p = 9-q.
// Lane bits = state bits 9..4 (qubits 0..5), reg bits = state bits 3..0
// (qubits 6..9).
__global__ __launch_bounds__(256)
void pqc_kernel(const float* __restrict__ x,
                const float* __restrict__ params,
                float* __restrict__ out, int B) {
    const int lane = threadIdx.x & 63;
    const int wave = threadIdx.x >> 6;
    const int b = blockIdx.x * 4 + wave;
    if (b >= B) return;

    float2 st[16];
#pragma unroll
    for (int r = 0; r < 16; ++r) st[r] = make_float2(0.f, 0.f);
    if (lane == 0) st[0].x = 1.0f;

    // ---- data encoding: RY(x[b,q]) ----
    const float* xb = x + (long)b * NQ;
    float c, s;
    __sincosf(0.5f * xb[0], &s, &c); ry_lane<32>(st, lane, c, s);
    __sincosf(0.5f * xb[1], &s, &c); ry_lane<16>(st, lane, c, s);
    __sincosf(0.5f * xb[2], &s, &c); ry_lane<8>(st, lane, c, s);
    __sincosf(0.5f * xb[3], &s, &c); ry_lane<4>(st, lane, c, s);
    __sincosf(0.5f * xb[4], &s, &c); ry_lane<2>(st, lane, c, s);
    __sincosf(0.5f * xb[5], &s, &c); ry_lane<1>(st, lane, c, s);
    __sincosf(0.5f * xb[6], &s, &c); ry_reg<8>(st, c, s);
    __sincosf(0.5f * xb[7], &s, &c); ry_reg<4>(st, c, s);
    __sincosf(0.5f * xb[8], &s, &c); ry_reg<2>(st, c, s);
    __sincosf(0.5f * xb[9], &s, &c); ry_reg<1>(st, c, s);

    // ---- variational layers ----
    // Per layer: RZ(z)@RY(y) per qubit = [global Z-diagonal] . [real RY's].
    // RYs on distinct qubits commute, so: all 10 real RYs, then one fused
    // diagonal, then the CNOT ring.
    // Last layer: the diagonal commutes through the ring as a diagonal and
    // cannot change |amp|^2 -> dropped; the ring itself is a basis
    // permutation -> folded into the readout sign masks (prefix-XOR).
#pragma unroll
    for (int l = 0; l < 4; ++l) {
        const float* pl = params + l * 2 * NQ;

        __sincosf(0.5f * pl[0], &s, &c); ry_lane<32>(st, lane, c, s);
        __sincosf(0.5f * pl[1], &s, &c); ry_lane<16>(st, lane, c, s);
        __sincosf(0.5f * pl[2], &s, &c); ry_lane<8>(st, lane, c, s);
        __sincosf(0.5f * pl[3], &s, &c); ry_lane<4>(st, lane, c, s);
        __sincosf(0.5f * pl[4], &s, &c); ry_lane<2>(st, lane, c, s);
        __sincosf(0.5f * pl[5], &s, &c); ry_lane<1>(st, lane, c, s);
        __sincosf(0.5f * pl[6], &s, &c); ry_reg<8>(st, c, s);
        __sincosf(0.5f * pl[7], &s, &c); ry_reg<4>(st, c, s);
        __sincosf(0.5f * pl[8], &s, &c); ry_reg<2>(st, c, s);
        __sincosf(0.5f * pl[9], &s, &c); ry_reg<1>(st, c, s);

        if (l < 3) {
            // ---- fused Z-diagonal: st[s] *= prod_q exp(i*(bit_q ? +hz_q : -hz_q))
            // lane-qubit part (qubits 0..5 <-> lane bits 32..1):
            float sz, cz;
            __sincosf(0.5f * pl[10], &sz, &cz);
            float2 PL = make_float2(cz, (lane & 32) ? sz : -sz);
            __sincosf(0.5f * pl[11], &sz, &cz);
            PL = cmul(PL, make_float2(cz, (lane & 16) ? sz : -sz));
            __sincosf(0.5f * pl[12], &sz, &cz);
            PL = cmul(PL, make_float2(cz, (lane & 8) ? sz : -sz));
            __sincosf(0.5f * pl[13], &sz, &cz);
            PL = cmul(PL, make_float2(cz, (lane & 4) ? sz : -sz));
            __sincosf(0.5f * pl[14], &sz, &cz);
            PL = cmul(PL, make_float2(cz, (lane & 2) ? sz : -sz));
            __sincosf(0.5f * pl[15], &sz, &cz);
            PL = cmul(PL, make_float2(cz, (lane & 1) ? sz : -sz));

            // reg-qubit part (qubits 6..9 <-> reg bits 8,4,2,1), product tree:
            float s6, c6, s7, c7, s8, c8, s9, c9;
            __sincosf(0.5f * pl[16], &s6, &c6);
            __sincosf(0.5f * pl[17], &s7, &c7);
            __sincosf(0.5f * pl[18], &s8, &c8);
            __sincosf(0.5f * pl[19], &s9, &c9);
            float2 A[4], Bb[4];
            A[0] = cmul(make_float2(c6, -s6), make_float2(c7, -s7));
            A[1] = cmul(make_float2(c6, -s6), make_float2(c7,  s7));
            A[2] = cmul(make_float2(c6,  s6), make_float2(c7, -s7));
            A[3] = cmul(make_float2(c6,  s6), make_float2(c7,  s7));
            Bb[0] = cmul(make_float2(c8, -s8), make_float2(c9, -s9));
            Bb[1] = cmul(make_float2(c8, -s8), make_float2(c9,  s9));
            Bb[2] = cmul(make_float2(c8,  s8), make_float2(c9, -s9));
            Bb[3] = cmul(make_float2(c8,  s8), make_float2(c9,  s9));
            // fold lane part into A to avoid a 16-wide temp array
            A[0] = cmul(A[0], PL); A[1] = cmul(A[1], PL);
            A[2] = cmul(A[2], PL); A[3] = cmul(A[3], PL);
#pragma unroll
            for (int r = 0; r < 16; ++r)
                st[r] = cmul(cmul(st[r], A[r >> 2]), Bb[r & 3]);

            // ---- CNOT ring ----
            // CNOTs (0,1)..(4,5) act only on lane bits; their composition's
            // inverse is the Gray-code map: src_lane = lane ^ (lane>>1).
            const int addr = ((lane ^ (lane >> 1)) & 63) << 2;
#pragma unroll
            for (int r = 0; r < 16; ++r) st[r] = bperm2(addr, st[r]);
            cnot_lane_reg<1, 8>(st, lane);   // CNOT(5,6)
            cnot_reg_reg<8, 4>(st);          // CNOT(6,7)
            cnot_reg_reg<4, 2>(st);          // CNOT(7,8)
            cnot_reg_reg<2, 1>(st);          // CNOT(8,9)
            cnot_reg_lane<1, 32>(st);        // CNOT(9,0)
        }
    }

    // ---- readout ----
    // Final ring folded into signs. Post-ring bit of qubit q is a parity of
    // pre-ring bits: q=0 -> state bits 0..8 (lane mask 31, reg mask 15);
    // q=k>=1 -> state bits (9-k)..9.
    // <Z_q> = WHT_{laneMask}[ per-lane sum with reg-parity signs ].
    float lane_sum = 0.f, A3 = 0.f, A32 = 0.f, A321 = 0.f, A3210 = 0.f;
#pragma unroll
    for (int r = 0; r < 16; ++r) {
        float p = st[r].x * st[r].x + st[r].y * st[r].y;
        const int p3 = (r >> 3) & 1;
        const int p32 = p3 ^ ((r >> 2) & 1);
        const int p321 = p32 ^ ((r >> 1) & 1);
        const int p3210 = p321 ^ (r & 1);
        lane_sum += p;
        A3    += p3    ? -p : p;
        A32   += p32   ? -p : p;
        A321  += p321  ? -p : p;
        A3210 += p3210 ? -p : p;
    }
    const float wLS   = wht64(lane_sum, lane);
    const float w3    = wht64(A3, lane);
    const float w32   = wht64(A32, lane);
    const float w321  = wht64(A321, lane);
    const float w3210 = wht64(A3210, lane);

    const long base = (long)b * NQ;
    // out[0]: lane mask 31 on A3210; out[1..5]: masks 48,56,60,62,63 on
    // lane_sum; out[6..9]: mask 63 on A3/A32/A321/A3210.
    if (lane == 31) out[base + 0] = w3210;
    if (lane == 48) out[base + 1] = wLS;
    if (lane == 56) out[base + 2] = wLS;
    if (lane == 60) out[base + 3] = wLS;
    if (lane == 62) out[base + 4] = wLS;
    if (lane == 63) {
        out[base + 5] = wLS;
        out[base + 6] = w3;
        out[base + 7] = w32;
        out[base + 8] = w321;
        out[base + 9] = w3210;
    }
}

extern "C" void kernel_launch(void* const* d_in, const int* in_sizes, int n_in,
                              void* d_out, int out_size, void* d_ws, size_t ws_size,
                              hipStream_t stream) {
    const float* x = (const float*)d_in[0];       // [B, 10]
    const float* params = (const float*)d_in[1];  // [4, 20]
    float* out = (float*)d_out;                   // [B, 10]
    const int B = in_sizes[0] / NQ;               // 4096
    const int waves_per_block = 4;                // 256 threads
    const int grid = (B + waves_per_block - 1) / waves_per_block;
    pqc_kernel<<<grid, 256, 0, stream>>>(x, params, out, B);
}

// Round 3
// 85.465 us; speedup vs baseline: 1.6811x; 1.2302x over previous
//
#include <hip/hip_runtime.h>

#define NQ 10

// ---------- cross-lane helpers ----------
// xor-1 / xor-2 via DPP quad_perm (VALU pipe, ~1cyc hazard);
// xor-4/8/16 via ds_swizzle BitMode; xor-32 via __shfl_xor (compiler picks).
template<int M>
__device__ __forceinline__ float lx(float v) {
    if constexpr (M == 1)
        return __int_as_float(__builtin_amdgcn_mov_dpp(__float_as_int(v), 0xB1, 0xF, 0xF, true));
    else if constexpr (M == 2)
        return __int_as_float(__builtin_amdgcn_mov_dpp(__float_as_int(v), 0x4E, 0xF, 0xF, true));
    else if constexpr (M == 4 || M == 8 || M == 16)
        return __int_as_float(__builtin_amdgcn_ds_swizzle(__float_as_int(v), (M << 10) | 0x1F));
    else
        return __shfl_xor(v, M, 64);
}

template<int M>
__device__ __forceinline__ float2 lx2(float2 v) {
    return make_float2(lx<M>(v.x), lx<M>(v.y));
}

__device__ __forceinline__ float2 cmul(float2 a, float2 b) {
    return make_float2(a.x * b.x - a.y * b.y, a.x * b.y + a.y * b.x);
}

__device__ __forceinline__ float2 bperm2(int addr, float2 v) {
    float2 r;
    r.x = __int_as_float(__builtin_amdgcn_ds_bpermute(addr, __float_as_int(v.x)));
    r.y = __int_as_float(__builtin_amdgcn_ds_bpermute(addr, __float_as_int(v.y)));
    return r;
}

// ---------- gates ----------
// Real RY on a LANE bit, real state.
template<int M>
__device__ __forceinline__ void ry_lane_r(float sr[16], int lane, float c, float s) {
    const float cB = (lane & M) ? s : -s;
#pragma unroll
    for (int r = 0; r < 16; ++r) {
        float part = lx<M>(sr[r]);
        sr[r] = c * sr[r] + cB * part;
    }
}

// Real RY on a REGISTER bit, real state.
template<int RB>
__device__ __forceinline__ void ry_reg_r(float sr[16], float c, float s) {
#pragma unroll
    for (int r = 0; r < 16; ++r) {
        if (r & RB) continue;
        float a0 = sr[r], a1 = sr[r | RB];
        sr[r]      = c * a0 - s * a1;
        sr[r | RB] = s * a0 + c * a1;
    }
}

// Real RY on a LANE bit, complex state.
template<int M>
__device__ __forceinline__ void ry_lane(float2 st[16], int lane, float c, float s) {
    const float cB = (lane & M) ? s : -s;
#pragma unroll
    for (int r = 0; r < 16; ++r) {
        float2 part = lx2<M>(st[r]);
        st[r].x = c * st[r].x + cB * part.x;
        st[r].y = c * st[r].y + cB * part.y;
    }
}

// Real RY on a REGISTER bit, complex state.
template<int RB>
__device__ __forceinline__ void ry_reg(float2 st[16], float c, float s) {
#pragma unroll
    for (int r = 0; r < 16; ++r) {
        if (r & RB) continue;
        float2 a0 = st[r], a1 = st[r | RB];
        st[r].x = c * a0.x - s * a1.x;
        st[r].y = c * a0.y - s * a1.y;
        st[r | RB].x = s * a0.x + c * a1.x;
        st[r | RB].y = s * a0.y + c * a1.y;
    }
}

// CNOT: control lane bit MC, target register bit RB.
template<int MC, int RB>
__device__ __forceinline__ void cnot_lane_reg(float2 st[16], int lane) {
    const bool sel = (lane & MC) != 0;
#pragma unroll
    for (int r = 0; r < 16; ++r) {
        if (r & RB) continue;
        float2 lo = st[r], hi = st[r | RB];
        st[r]      = sel ? hi : lo;
        st[r | RB] = sel ? lo : hi;
    }
}

// CNOT: control register bit RC, target register bit RT — free permutation.
template<int RC, int RT>
__device__ __forceinline__ void cnot_reg_reg(float2 st[16]) {
#pragma unroll
    for (int r = 0; r < 16; ++r) {
        if ((r & RC) && !(r & RT)) {
            float2 t = st[r];
            st[r] = st[r | RT];
            st[r | RT] = t;
        }
    }
}

// CNOT: control register bit RC, target lane bit MT.
template<int RC, int MT>
__device__ __forceinline__ void cnot_reg_lane(float2 st[16]) {
#pragma unroll
    for (int r = 0; r < 16; ++r) {
        if (r & RC) st[r] = lx2<MT>(st[r]);
    }
}

// 64-point Walsh-Hadamard across lanes: lane m ends with sum_l (-1)^popc(m&l) v_l.
__device__ __forceinline__ float wht64(float v, int lane) {
    float t;
    t = lx<1>(v);  v = (lane & 1)  ? (t - v) : (v + t);
    t = lx<2>(v);  v = (lane & 2)  ? (t - v) : (v + t);
    t = lx<4>(v);  v = (lane & 4)  ? (t - v) : (v + t);
    t = lx<8>(v);  v = (lane & 8)  ? (t - v) : (v + t);
    t = lx<16>(v); v = (lane & 16) ? (t - v) : (v + t);
    t = lx<32>(v); v = (lane & 32) ? (t - v) : (v + t);
    return v;
}

// ---------- main kernel: one wave per batch sample ----------
// State layout: s = lane*16 + r ; qubit q <-> state bit p = 9-q.
// Lane bits = state bits 9..4 (qubits 0..5), reg bits 3..0 (qubits 6..9).
__global__ __launch_bounds__(256)
void pqc_kernel(const float* __restrict__ x,
                const float* __restrict__ params,
                float* __restrict__ out, int B) {
    const int lane = threadIdx.x & 63;
    const int wave = threadIdx.x >> 6;
    const int b = blockIdx.x * 4 + wave;
    if (b >= B) return;

    // ---- encoding: |psi> = prod_q RY(x_q)|0> is a product state ----
    const float* xb = x + (long)b * NQ;
    float c0,s0,c1,s1,c2,s2,c3,s3,c4,s4,c5,s5,c6,s6,c7,s7,c8,s8,c9,s9;
    __sincosf(0.5f * xb[0], &s0, &c0);
    __sincosf(0.5f * xb[1], &s1, &c1);
    __sincosf(0.5f * xb[2], &s2, &c2);
    __sincosf(0.5f * xb[3], &s3, &c3);
    __sincosf(0.5f * xb[4], &s4, &c4);
    __sincosf(0.5f * xb[5], &s5, &c5);
    __sincosf(0.5f * xb[6], &s6, &c6);
    __sincosf(0.5f * xb[7], &s7, &c7);
    __sincosf(0.5f * xb[8], &s8, &c8);
    __sincosf(0.5f * xb[9], &s9, &c9);
    float laneprod = ((lane & 32) ? s0 : c0) * ((lane & 16) ? s1 : c1)
                   * ((lane & 8)  ? s2 : c2) * ((lane & 4)  ? s3 : c3)
                   * ((lane & 2)  ? s4 : c4) * ((lane & 1)  ? s5 : c5);
    float Ar[4] = { c6 * c7, c6 * s7, s6 * c7, s6 * s7 };
    float Br[4] = { c8 * c9, c8 * s9, s8 * c9, s8 * s9 };
    Ar[0] *= laneprod; Ar[1] *= laneprod; Ar[2] *= laneprod; Ar[3] *= laneprod;

    float sr[16];
#pragma unroll
    for (int r = 0; r < 16; ++r) sr[r] = Ar[r >> 2] * Br[r & 3];

    // ---- layer 0: RYs on a purely REAL state ----
    const float* p0 = params;
    float c, s;
    __sincosf(0.5f * p0[0], &s, &c); ry_lane_r<32>(sr, lane, c, s);
    __sincosf(0.5f * p0[1], &s, &c); ry_lane_r<16>(sr, lane, c, s);
    __sincosf(0.5f * p0[2], &s, &c); ry_lane_r<8>(sr, lane, c, s);
    __sincosf(0.5f * p0[3], &s, &c); ry_lane_r<4>(sr, lane, c, s);
    __sincosf(0.5f * p0[4], &s, &c); ry_lane_r<2>(sr, lane, c, s);
    __sincosf(0.5f * p0[5], &s, &c); ry_lane_r<1>(sr, lane, c, s);
    __sincosf(0.5f * p0[6], &s, &c); ry_reg_r<8>(sr, c, s);
    __sincosf(0.5f * p0[7], &s, &c); ry_reg_r<4>(sr, c, s);
    __sincosf(0.5f * p0[8], &s, &c); ry_reg_r<2>(sr, c, s);
    __sincosf(0.5f * p0[9], &s, &c); ry_reg_r<1>(sr, c, s);

    // ---- layer 0 fused Z-diagonal (real -> complex) ----
    float2 st[16];
    {
        float sz, cz;
        __sincosf(0.5f * p0[10], &sz, &cz);
        float2 PL = make_float2(cz, (lane & 32) ? sz : -sz);
        __sincosf(0.5f * p0[11], &sz, &cz);
        PL = cmul(PL, make_float2(cz, (lane & 16) ? sz : -sz));
        __sincosf(0.5f * p0[12], &sz, &cz);
        PL = cmul(PL, make_float2(cz, (lane & 8) ? sz : -sz));
        __sincosf(0.5f * p0[13], &sz, &cz);
        PL = cmul(PL, make_float2(cz, (lane & 4) ? sz : -sz));
        __sincosf(0.5f * p0[14], &sz, &cz);
        PL = cmul(PL, make_float2(cz, (lane & 2) ? sz : -sz));
        __sincosf(0.5f * p0[15], &sz, &cz);
        PL = cmul(PL, make_float2(cz, (lane & 1) ? sz : -sz));

        float z6s, z6c, z7s, z7c, z8s, z8c, z9s, z9c;
        __sincosf(0.5f * p0[16], &z6s, &z6c);
        __sincosf(0.5f * p0[17], &z7s, &z7c);
        __sincosf(0.5f * p0[18], &z8s, &z8c);
        __sincosf(0.5f * p0[19], &z9s, &z9c);
        float2 A[4], Bb[4];
        A[0] = cmul(make_float2(z6c, -z6s), make_float2(z7c, -z7s));
        A[1] = cmul(make_float2(z6c, -z6s), make_float2(z7c,  z7s));
        A[2] = cmul(make_float2(z6c,  z6s), make_float2(z7c, -z7s));
        A[3] = cmul(make_float2(z6c,  z6s), make_float2(z7c,  z7s));
        Bb[0] = cmul(make_float2(z8c, -z8s), make_float2(z9c, -z9s));
        Bb[1] = cmul(make_float2(z8c, -z8s), make_float2(z9c,  z9s));
        Bb[2] = cmul(make_float2(z8c,  z8s), make_float2(z9c, -z9s));
        Bb[3] = cmul(make_float2(z8c,  z8s), make_float2(z9c,  z9s));
        A[0] = cmul(A[0], PL); A[1] = cmul(A[1], PL);
        A[2] = cmul(A[2], PL); A[3] = cmul(A[3], PL);
#pragma unroll
        for (int r = 0; r < 16; ++r) {
            float2 t = make_float2(sr[r] * A[r >> 2].x, sr[r] * A[r >> 2].y);
            st[r] = cmul(t, Bb[r & 3]);
        }
    }

    // ---- layer 0 CNOT ring ----
    {
        const int addr = ((lane ^ (lane >> 1)) & 63) << 2;
#pragma unroll
        for (int r = 0; r < 16; ++r) st[r] = bperm2(addr, st[r]);
        cnot_lane_reg<1, 8>(st, lane);
        cnot_reg_reg<8, 4>(st);
        cnot_reg_reg<4, 2>(st);
        cnot_reg_reg<2, 1>(st);
        cnot_reg_lane<1, 32>(st);
    }

    // ---- layers 1..3 (complex). Last layer: diagonal+ring folded away. ----
#pragma unroll
    for (int l = 1; l < 4; ++l) {
        const float* pl = params + l * 2 * NQ;

        __sincosf(0.5f * pl[0], &s, &c); ry_lane<32>(st, lane, c, s);
        __sincosf(0.5f * pl[1], &s, &c); ry_lane<16>(st, lane, c, s);
        __sincosf(0.5f * pl[2], &s, &c); ry_lane<8>(st, lane, c, s);
        __sincosf(0.5f * pl[3], &s, &c); ry_lane<4>(st, lane, c, s);
        __sincosf(0.5f * pl[4], &s, &c); ry_lane<2>(st, lane, c, s);
        __sincosf(0.5f * pl[5], &s, &c); ry_lane<1>(st, lane, c, s);
        __sincosf(0.5f * pl[6], &s, &c); ry_reg<8>(st, c, s);
        __sincosf(0.5f * pl[7], &s, &c); ry_reg<4>(st, c, s);
        __sincosf(0.5f * pl[8], &s, &c); ry_reg<2>(st, c, s);
        __sincosf(0.5f * pl[9], &s, &c); ry_reg<1>(st, c, s);

        if (l < 3) {
            float sz, cz;
            __sincosf(0.5f * pl[10], &sz, &cz);
            float2 PL = make_float2(cz, (lane & 32) ? sz : -sz);
            __sincosf(0.5f * pl[11], &sz, &cz);
            PL = cmul(PL, make_float2(cz, (lane & 16) ? sz : -sz));
            __sincosf(0.5f * pl[12], &sz, &cz);
            PL = cmul(PL, make_float2(cz, (lane & 8) ? sz : -sz));
            __sincosf(0.5f * pl[13], &sz, &cz);
            PL = cmul(PL, make_float2(cz, (lane & 4) ? sz : -sz));
            __sincosf(0.5f * pl[14], &sz, &cz);
            PL = cmul(PL, make_float2(cz, (lane & 2) ? sz : -sz));
            __sincosf(0.5f * pl[15], &sz, &cz);
            PL = cmul(PL, make_float2(cz, (lane & 1) ? sz : -sz));

            float z6s, z6c, z7s, z7c, z8s, z8c, z9s, z9c;
            __sincosf(0.5f * pl[16], &z6s, &z6c);
            __sincosf(0.5f * pl[17], &z7s, &z7c);
            __sincosf(0.5f * pl[18], &z8s, &z8c);
            __sincosf(0.5f * pl[19], &z9s, &z9c);
            float2 A[4], Bb[4];
            A[0] = cmul(make_float2(z6c, -z6s), make_float2(z7c, -z7s));
            A[1] = cmul(make_float2(z6c, -z6s), make_float2(z7c,  z7s));
            A[2] = cmul(make_float2(z6c,  z6s), make_float2(z7c, -z7s));
            A[3] = cmul(make_float2(z6c,  z6s), make_float2(z7c,  z7s));
            Bb[0] = cmul(make_float2(z8c, -z8s), make_float2(z9c, -z9s));
            Bb[1] = cmul(make_float2(z8c, -z8s), make_float2(z9c,  z9s));
            Bb[2] = cmul(make_float2(z8c,  z8s), make_float2(z9c, -z9s));
            Bb[3] = cmul(make_float2(z8c,  z8s), make_float2(z9c,  z9s));
            A[0] = cmul(A[0], PL); A[1] = cmul(A[1], PL);
            A[2] = cmul(A[2], PL); A[3] = cmul(A[3], PL);
#pragma unroll
            for (int r = 0; r < 16; ++r)
                st[r] = cmul(cmul(st[r], A[r >> 2]), Bb[r & 3]);

            const int addr = ((lane ^ (lane >> 1)) & 63) << 2;
#pragma unroll
            for (int r = 0; r < 16; ++r) st[r] = bperm2(addr, st[r]);
            cnot_lane_reg<1, 8>(st, lane);
            cnot_reg_reg<8, 4>(st);
            cnot_reg_reg<4, 2>(st);
            cnot_reg_reg<2, 1>(st);
            cnot_reg_lane<1, 32>(st);
        }
    }

    // ---- readout (final ring folded into parity signs) ----
    float lane_sum = 0.f, A3 = 0.f, A32 = 0.f, A321 = 0.f, A3210 = 0.f;
#pragma unroll
    for (int r = 0; r < 16; ++r) {
        float p = st[r].x * st[r].x + st[r].y * st[r].y;
        const int p3 = (r >> 3) & 1;
        const int p32 = p3 ^ ((r >> 2) & 1);
        const int p321 = p32 ^ ((r >> 1) & 1);
        const int p3210 = p321 ^ (r & 1);
        lane_sum += p;
        A3    += p3    ? -p : p;
        A32   += p32   ? -p : p;
        A321  += p321  ? -p : p;
        A3210 += p3210 ? -p : p;
    }
    const float wLS   = wht64(lane_sum, lane);
    const float w3    = wht64(A3, lane);
    const float w32   = wht64(A32, lane);
    const float w321  = wht64(A321, lane);
    const float w3210 = wht64(A3210, lane);

    const long base = (long)b * NQ;
    if (lane == 31) out[base + 0] = w3210;
    if (lane == 48) out[base + 1] = wLS;
    if (lane == 56) out[base + 2] = wLS;
    if (lane == 60) out[base + 3] = wLS;
    if (lane == 62) out[base + 4] = wLS;
    if (lane == 63) {
        out[base + 5] = wLS;
        out[base + 6] = w3;
        out[base + 7] = w32;
        out[base + 8] = w321;
        out[base + 9] = w3210;
    }
}

extern "C" void kernel_launch(void* const* d_in, const int* in_sizes, int n_in,
                              void* d_out, int out_size, void* d_ws, size_t ws_size,
                              hipStream_t stream) {
    const float* x = (const float*)d_in[0];       // [B, 10]
    const float* params = (const float*)d_in[1];  // [4, 20]
    float* out = (float*)d_out;                   // [B, 10]
    const int B = in_sizes[0] / NQ;               // 4096
    const int grid = (B + 3) / 4;                 // 4 waves (samples) per block
    pqc_kernel<<<grid, 256, 0, stream>>>(x, params, out, B);
}